// Round 4
// baseline (1143.266 us; speedup 1.0000x reference)
//
#include <hip/hip_runtime.h>
#include <stdint.h>

// Problem constants (match reference)
#define T_TOK 8192
#define HID   1024
#define INTER 4096
#define NE    8
#define TOPK  2
#define CAP   2048            // min(ceil(T*K*CF/E), T) = 2048
#define EC    (NE * CAP)      // 16384 slots

// Workspace layout (bytes).
//  [0,   64MB)  WgT  bf16 (E, INTER, HID)   gate_w transposed
//  [64,  128MB) WuT  bf16 (E, INTER, HID)
//  [128, 192MB) WdT  bf16 (E, HID, INTER)   down_w transposed
//  [192, 224MB) Xe   bf16 (EC, HID)         gathered tokens
//  [224, 352MB) interB bf16 (EC, INTER)     silu(g)*u
//  [352, 384MB) pout bf16 (EC, HID)         permuted expert output
//  [416MB .. )  perm int (T,2), assign int (EC)

typedef __attribute__((ext_vector_type(8))) short bf16x8;
typedef __attribute__((ext_vector_type(4))) float f32x4;
typedef __attribute__((ext_vector_type(16))) float f32x16;

static __device__ __forceinline__ unsigned short f2bf(float f) {
    union { float f; unsigned u; } a; a.f = f;
    unsigned r = a.u + 0x7FFFu + ((a.u >> 16) & 1u);   // round-nearest-even
    return (unsigned short)(r >> 16);
}
static __device__ __forceinline__ float bf2f(unsigned short b) {
    union { unsigned u; float f; } a; a.u = ((unsigned)b) << 16;
    return a.f;
}

static __device__ __forceinline__ void gload(const unsigned short* g, unsigned short* l) {
    // async global->LDS, 16B/lane; LDS dest = wave-uniform base + lane*16
    __builtin_amdgcn_global_load_lds((__attribute__((address_space(1))) void*)(uintptr_t)g,
                                     (__attribute__((address_space(3))) void*)l, 16, 0, 0);
}

#define BAR() do { asm volatile("" ::: "memory"); __builtin_amdgcn_s_barrier(); asm volatile("" ::: "memory"); } while (0)
#define WAITVM(N) asm volatile("s_waitcnt vmcnt(" #N ")" ::: "memory")

// ---------------------------------------------------------------- routing ---
__global__ __launch_bounds__(512) void route_kernel(const int* __restrict__ eidx,
                                                    int* __restrict__ perm,
                                                    int* __restrict__ assign) {
    int tid = threadIdx.x;
    for (int i = tid; i < EC; i += 512) assign[i] = 0;   // empty slot -> token 0
    __syncthreads();
    int e = tid >> 6;          // wave index == expert
    int lane = tid & 63;
    const int TPL = T_TOK / 64;                          // 128 tokens per lane
    int t0 = lane * TPL;
    int cnt = 0;
    for (int t = t0; t < t0 + TPL; ++t) {
        int e0 = eidx[t * 2], e1 = eidx[t * 2 + 1];
        cnt += (e0 == e) + (e1 == e);
    }
    int incl = cnt;
    #pragma unroll
    for (int off = 1; off < 64; off <<= 1) {
        int n = __shfl_up(incl, off, 64);
        if (lane >= off) incl += n;
    }
    int run = incl - cnt;
    for (int t = t0; t < t0 + TPL; ++t) {
        int e0 = eidx[t * 2], e1 = eidx[t * 2 + 1];
        int c = (e0 == e) + (e1 == e);
        if (c) {
            run += c;
            int pos = run;                       // inclusive (1-based)
            bool keep = (pos <= CAP);
            int pi = keep ? (pos + e * CAP) : 0;
            if (e0 == e) perm[t * 2]     = pi;
            if (e1 == e) perm[t * 2 + 1] = pi;
            if (keep) assign[pi - 1] = t;
        }
    }
}

// --------------------------------------------------- transpose + fp32->bf16 --
__global__ __launch_bounds__(256) void transpose_cvt2(const float* __restrict__ in0,
                                                      unsigned short* __restrict__ out0,
                                                      const float* __restrict__ in1,
                                                      unsigned short* __restrict__ out1) {
    __shared__ unsigned short tile[64][68];
    int z = blockIdx.z;
    const float* in = (z < 8) ? in0 : in1;
    unsigned short* out = (z < 8) ? out0 : out1;
    int e = z & 7;
    const int R = HID, Cc = INTER;
    const float* inp = in + (size_t)e * R * Cc;
    unsigned short* outp = out + (size_t)e * R * Cc;
    int c0 = blockIdx.x * 64, r0 = blockIdx.y * 64;
    int t = threadIdx.x;
    int x = t & 15;
    int ry = t >> 4;
    #pragma unroll
    for (int j = 0; j < 4; ++j) {
        int row = ry + 16 * j;
        float4 v = *(const float4*)(inp + (size_t)(r0 + row) * Cc + c0 + 4 * x);
        ushort4 o;
        o.x = f2bf(v.x); o.y = f2bf(v.y); o.z = f2bf(v.z); o.w = f2bf(v.w);
        *(ushort4*)&tile[row][4 * x] = o;
    }
    __syncthreads();
    #pragma unroll
    for (int j = 0; j < 4; ++j) {
        int oc = ry + 16 * j;
        ushort4 o;
        o.x = tile[4 * x + 0][oc];
        o.y = tile[4 * x + 1][oc];
        o.z = tile[4 * x + 2][oc];
        o.w = tile[4 * x + 3][oc];
        *(ushort4*)(outp + (size_t)(c0 + oc) * R + r0 + 4 * x) = o;
    }
}

__global__ __launch_bounds__(256) void transpose_cvt(const float* __restrict__ in,
                                                     unsigned short* __restrict__ out,
                                                     int R, int Cc) {
    __shared__ unsigned short tile[64][68];
    int e = blockIdx.z;
    const float* inp = in + (size_t)e * R * Cc;
    unsigned short* outp = out + (size_t)e * R * Cc;
    int c0 = blockIdx.x * 64, r0 = blockIdx.y * 64;
    int t = threadIdx.x;
    int x = t & 15;
    int ry = t >> 4;
    #pragma unroll
    for (int j = 0; j < 4; ++j) {
        int row = ry + 16 * j;
        float4 v = *(const float4*)(inp + (size_t)(r0 + row) * Cc + c0 + 4 * x);
        ushort4 o;
        o.x = f2bf(v.x); o.y = f2bf(v.y); o.z = f2bf(v.z); o.w = f2bf(v.w);
        *(ushort4*)&tile[row][4 * x] = o;
    }
    __syncthreads();
    #pragma unroll
    for (int j = 0; j < 4; ++j) {
        int oc = ry + 16 * j;
        ushort4 o;
        o.x = tile[4 * x + 0][oc];
        o.y = tile[4 * x + 1][oc];
        o.z = tile[4 * x + 2][oc];
        o.w = tile[4 * x + 3][oc];
        *(ushort4*)(outp + (size_t)(c0 + oc) * R + r0 + 4 * x) = o;
    }
}

// ------------------------------------------------------- gather + cvt tokens -
__global__ __launch_bounds__(256) void gather_cvt(const float* __restrict__ hs,
                                                  const int* __restrict__ assign,
                                                  unsigned short* __restrict__ xe) {
    int s = blockIdx.x;
    int tok = assign[s];
    const float* src = hs + (size_t)tok * HID;
    unsigned short* dst = xe + (size_t)s * HID;
    int h = threadIdx.x * 4;
    float4 v = *(const float4*)(src + h);
    ushort4 o;
    o.x = f2bf(v.x); o.y = f2bf(v.y); o.z = f2bf(v.z); o.w = f2bf(v.w);
    *(ushort4*)(dst + h) = o;
}

// =============================================================================
// R4 = R3 + prologue race fix.
// 32x32x16 MFMA, A through LDS (swizzled), B global->reg direct.
// 256 thr = 4 waves (2M x 2N); BM=256, BK=32; per-wave 128M.
// LDS: 3 x 16 KiB A buffers (48 KiB) -> 2 blocks/CU (96 KiB), two independent
// barrier groups overlap MFMA vs LDS/VMEM phases (m114).
// A swizzle: LDS chunk c of row r holds global chunk c ^ ((r>>1)&3) (16B
// chunks, 64B rows). Writer pre-swizzles global col (rule #21).
// RACE FIX (R3 bug): prologue must end with WAITVM(8)+BAR so tile 0's staging
// is complete (across ALL waves — vmcnt is per-wave) before t=0's ds_reads.
// Loop invariant: at iter t's WAITVM(4), queue = [tile t+1 stages][B loads]
// [tile t+2 stages]; wait-to-4 retires all but tile t+2's stages.
// =============================================================================

#define BUFE 8192   // elems per A buffer (256 x 32)

// ------------------------------- fused gate+up GEMM + SiLU*mul (dual acc) ----
__global__ __launch_bounds__(256, 2) void gateup_gemm(const unsigned short* __restrict__ Xe,
                                                      const unsigned short* __restrict__ WgT,
                                                      const unsigned short* __restrict__ WuT,
                                                      unsigned short* __restrict__ interB) {
    extern __shared__ __align__(16) unsigned short smemU[];
    const int K = HID;          // 1024
    const int NT = K / 32;      // 32 K-tiles

    int e  = blockIdx.x;                 // x fastest -> XCD-pinned per expert
    int m0 = blockIdx.y * 256;
    int n0 = blockIdx.z * 64;

    int tid = threadIdx.x;
    int lane = tid & 63, w = tid >> 6;
    int r = lane & 31, hi2 = lane >> 5;
    int wm = w >> 1, wn = w & 1;

    // A read offsets (elems within buffer): row=wm*128+mi*32+r, chunk swizzle
    int q = (r >> 1) & 3;
    const int aOff0 = wm * 4096 + r * 32 + ((hi2 ^ q) << 3);          // kk=0
    const int aOff1 = wm * 4096 + r * 32 + (((2 | hi2) ^ q) << 3);    // kk=1

    // A stage source (global col pre-swizzled to match linear LDS dest)
    int sr = lane >> 2;
    int sc = ((lane & 3) ^ ((lane >> 3) & 3)) << 3;
    const unsigned short* aS = Xe + ((size_t)e * CAP + m0 + w * 64 + sr) * K + sc;
    const int dA = w * 2048;   // + j*512

    // B pointers: global->reg, frag = 32 n-rows x 16 k, lane: n=r, k=hi2*8
    const unsigned short* gP = WgT + ((size_t)e * INTER + n0 + wn * 32 + r) * K + hi2 * 8;
    const unsigned short* uP = WuT + ((size_t)e * INTER + n0 + wn * 32 + r) * K + hi2 * 8;

    f32x16 accG[4], accU[4];
    f32x16 zero = {0.f,0.f,0.f,0.f,0.f,0.f,0.f,0.f,0.f,0.f,0.f,0.f,0.f,0.f,0.f,0.f};
    #pragma unroll
    for (int i = 0; i < 4; ++i) { accG[i] = zero; accU[i] = zero; }

    unsigned short* p0 = smemU;
    unsigned short* p1 = smemU + BUFE;
    unsigned short* p2 = smemU + 2 * BUFE;

    // prologue: stage A(0)->p0, A(1)->p1; load B(0) into regs
    #pragma unroll
    for (int j = 0; j < 4; ++j) gload(aS + (size_t)j * 16 * K, p0 + dA + j * 512);
    #pragma unroll
    for (int j = 0; j < 4; ++j) gload(aS + (size_t)j * 16 * K + 32, p1 + dA + j * 512);
    bf16x8 bG0 = *(const bf16x8*)(gP);
    bf16x8 bG1 = *(const bf16x8*)(gP + 16);
    bf16x8 bU0 = *(const bf16x8*)(uP);
    bf16x8 bU1 = *(const bf16x8*)(uP + 16);
    WAITVM(8);   // retire tile-0 stages (oldest 4); tile-1 + B stay in flight
    BAR();       // all waves' tile-0 staging visible before t=0 ds_reads

    bf16x8 aF0[4], aF1[4];
    int gk = 64;
    for (int t = 0; t < NT - 2; ++t) {
        #pragma unroll
        for (int mi = 0; mi < 4; ++mi) aF0[mi] = *(const bf16x8*)(p0 + aOff0 + mi * 1024);
        #pragma unroll
        for (int j = 0; j < 4; ++j) gload(aS + (size_t)j * 16 * K + gk, p2 + dA + j * 512);
        WAITVM(4);
        BAR();
        __builtin_amdgcn_s_setprio(1);
        #pragma unroll
        for (int mi = 0; mi < 4; ++mi) aF1[mi] = *(const bf16x8*)(p0 + aOff1 + mi * 1024);
        bf16x8 nG0 = *(const bf16x8*)(gP + 32);
        bf16x8 nG1 = *(const bf16x8*)(gP + 48);
        bf16x8 nU0 = *(const bf16x8*)(uP + 32);
        bf16x8 nU1 = *(const bf16x8*)(uP + 48);
        #pragma unroll
        for (int mi = 0; mi < 4; ++mi) {
            accG[mi] = __builtin_amdgcn_mfma_f32_32x32x16_bf16(aF0[mi], bG0, accG[mi], 0, 0, 0);
            accU[mi] = __builtin_amdgcn_mfma_f32_32x32x16_bf16(aF0[mi], bU0, accU[mi], 0, 0, 0);
        }
        #pragma unroll
        for (int mi = 0; mi < 4; ++mi) {
            accG[mi] = __builtin_amdgcn_mfma_f32_32x32x16_bf16(aF1[mi], bG1, accG[mi], 0, 0, 0);
            accU[mi] = __builtin_amdgcn_mfma_f32_32x32x16_bf16(aF1[mi], bU1, accU[mi], 0, 0, 0);
        }
        __builtin_amdgcn_s_setprio(0);
        BAR();
        bG0 = nG0; bG1 = nG1; bU0 = nU0; bU1 = nU1;
        gP += 32; uP += 32;
        unsigned short* tmp = p0; p0 = p1; p1 = p2; p2 = tmp;
        gk += 32;
    }
    // peeled t = NT-2 (no stage; drain)
    {
        #pragma unroll
        for (int mi = 0; mi < 4; ++mi) aF0[mi] = *(const bf16x8*)(p0 + aOff0 + mi * 1024);
        WAITVM(0);
        BAR();
        #pragma unroll
        for (int mi = 0; mi < 4; ++mi) aF1[mi] = *(const bf16x8*)(p0 + aOff1 + mi * 1024);
        bf16x8 nG0 = *(const bf16x8*)(gP + 32);
        bf16x8 nG1 = *(const bf16x8*)(gP + 48);
        bf16x8 nU0 = *(const bf16x8*)(uP + 32);
        bf16x8 nU1 = *(const bf16x8*)(uP + 48);
        #pragma unroll
        for (int mi = 0; mi < 4; ++mi) {
            accG[mi] = __builtin_amdgcn_mfma_f32_32x32x16_bf16(aF0[mi], bG0, accG[mi], 0, 0, 0);
            accU[mi] = __builtin_amdgcn_mfma_f32_32x32x16_bf16(aF0[mi], bU0, accU[mi], 0, 0, 0);
            accG[mi] = __builtin_amdgcn_mfma_f32_32x32x16_bf16(aF1[mi], bG1, accG[mi], 0, 0, 0);
            accU[mi] = __builtin_amdgcn_mfma_f32_32x32x16_bf16(aF1[mi], bU1, accU[mi], 0, 0, 0);
        }
        BAR();
        bG0 = nG0; bG1 = nG1; bU0 = nU0; bU1 = nU1;
    }
    // peeled t = NT-1
    {
        #pragma unroll
        for (int mi = 0; mi < 4; ++mi) aF0[mi] = *(const bf16x8*)(p1 + aOff0 + mi * 1024);
        #pragma unroll
        for (int mi = 0; mi < 4; ++mi) aF1[mi] = *(const bf16x8*)(p1 + aOff1 + mi * 1024);
        #pragma unroll
        for (int mi = 0; mi < 4; ++mi) {
            accG[mi] = __builtin_amdgcn_mfma_f32_32x32x16_bf16(aF0[mi], bG0, accG[mi], 0, 0, 0);
            accU[mi] = __builtin_amdgcn_mfma_f32_32x32x16_bf16(aF0[mi], bU0, accU[mi], 0, 0, 0);
            accG[mi] = __builtin_amdgcn_mfma_f32_32x32x16_bf16(aF1[mi], bG1, accG[mi], 0, 0, 0);
            accU[mi] = __builtin_amdgcn_mfma_f32_32x32x16_bf16(aF1[mi], bU1, accU[mi], 0, 0, 0);
        }
    }

    // epilogue: silu(G)*U -> bounce [256][72] -> vector stores
    __syncthreads();
    unsigned short* bounce = smemU;
    int col = wn * 32 + r;
    #pragma unroll
    for (int mi = 0; mi < 4; ++mi) {
        f32x16 g16 = accG[mi], u16 = accU[mi];
        #pragma unroll
        for (int rg = 0; rg < 16; ++rg) {
            int row = wm * 128 + mi * 32 + (rg & 3) + 8 * (rg >> 2) + 4 * hi2;
            float g = g16[rg];
            float s = g / (1.f + __expf(-g)) * u16[rg];
            bounce[row * 72 + col] = f2bf(s);
        }
    }
    __syncthreads();
    {
        unsigned short* Op = interB + ((size_t)e * CAP + m0) * INTER + n0;
        int rr = tid >> 3, cc = (tid & 7) * 8;
        #pragma unroll
        for (int j = 0; j < 8; ++j) {
            int row = rr + 32 * j;
            bf16x8 v = *(const bf16x8*)&bounce[row * 72 + cc];
            *(bf16x8*)(Op + (size_t)row * INTER + cc) = v;
        }
    }
}

// ------------------------------------------------------------- down GEMM ----
__global__ __launch_bounds__(256, 2) void down_gemm(const unsigned short* __restrict__ interB,
                                                    const unsigned short* __restrict__ WdT,
                                                    unsigned short* __restrict__ pout) {
    extern __shared__ __align__(16) unsigned short smemU[];
    const int K = INTER;        // 4096
    const int NT = K / 32;      // 128 K-tiles

    int e  = blockIdx.x;
    int m0 = blockIdx.y * 256;
    int n0 = blockIdx.z * 128;

    int tid = threadIdx.x;
    int lane = tid & 63, w = tid >> 6;
    int r = lane & 31, hi2 = lane >> 5;
    int wm = w >> 1, wn = w & 1;

    int q = (r >> 1) & 3;
    const int aOff0 = wm * 4096 + r * 32 + ((hi2 ^ q) << 3);
    const int aOff1 = wm * 4096 + r * 32 + (((2 | hi2) ^ q) << 3);

    int sr = lane >> 2;
    int sc = ((lane & 3) ^ ((lane >> 3) & 3)) << 3;
    const unsigned short* aS = interB + ((size_t)e * CAP + m0 + w * 64 + sr) * K + sc;
    const int dA = w * 2048;

    // B: per-wave cols wn*64 + ni*32 + r
    const unsigned short* dP0 = WdT + ((size_t)e * HID + n0 + wn * 64 + r) * K + hi2 * 8;
    const unsigned short* dP1 = dP0 + (size_t)32 * K;

    f32x16 acc[4][2];
    f32x16 zero = {0.f,0.f,0.f,0.f,0.f,0.f,0.f,0.f,0.f,0.f,0.f,0.f,0.f,0.f,0.f,0.f};
    #pragma unroll
    for (int i = 0; i < 4; ++i) { acc[i][0] = zero; acc[i][1] = zero; }

    unsigned short* p0 = smemU;
    unsigned short* p1 = smemU + BUFE;
    unsigned short* p2 = smemU + 2 * BUFE;

    #pragma unroll
    for (int j = 0; j < 4; ++j) gload(aS + (size_t)j * 16 * K, p0 + dA + j * 512);
    #pragma unroll
    for (int j = 0; j < 4; ++j) gload(aS + (size_t)j * 16 * K + 32, p1 + dA + j * 512);
    bf16x8 b00 = *(const bf16x8*)(dP0);
    bf16x8 b01 = *(const bf16x8*)(dP0 + 16);
    bf16x8 b10 = *(const bf16x8*)(dP1);
    bf16x8 b11 = *(const bf16x8*)(dP1 + 16);
    WAITVM(8);   // retire tile-0 stages; tile-1 + B stay in flight
    BAR();

    bf16x8 aF0[4], aF1[4];
    int gk = 64;
    for (int t = 0; t < NT - 2; ++t) {
        #pragma unroll
        for (int mi = 0; mi < 4; ++mi) aF0[mi] = *(const bf16x8*)(p0 + aOff0 + mi * 1024);
        #pragma unroll
        for (int j = 0; j < 4; ++j) gload(aS + (size_t)j * 16 * K + gk, p2 + dA + j * 512);
        WAITVM(4);
        BAR();
        __builtin_amdgcn_s_setprio(1);
        #pragma unroll
        for (int mi = 0; mi < 4; ++mi) aF1[mi] = *(const bf16x8*)(p0 + aOff1 + mi * 1024);
        bf16x8 n00 = *(const bf16x8*)(dP0 + 32);
        bf16x8 n01 = *(const bf16x8*)(dP0 + 48);
        bf16x8 n10 = *(const bf16x8*)(dP1 + 32);
        bf16x8 n11 = *(const bf16x8*)(dP1 + 48);
        #pragma unroll
        for (int mi = 0; mi < 4; ++mi) {
            acc[mi][0] = __builtin_amdgcn_mfma_f32_32x32x16_bf16(aF0[mi], b00, acc[mi][0], 0, 0, 0);
            acc[mi][1] = __builtin_amdgcn_mfma_f32_32x32x16_bf16(aF0[mi], b10, acc[mi][1], 0, 0, 0);
        }
        #pragma unroll
        for (int mi = 0; mi < 4; ++mi) {
            acc[mi][0] = __builtin_amdgcn_mfma_f32_32x32x16_bf16(aF1[mi], b01, acc[mi][0], 0, 0, 0);
            acc[mi][1] = __builtin_amdgcn_mfma_f32_32x32x16_bf16(aF1[mi], b11, acc[mi][1], 0, 0, 0);
        }
        __builtin_amdgcn_s_setprio(0);
        BAR();
        b00 = n00; b01 = n01; b10 = n10; b11 = n11;
        dP0 += 32; dP1 += 32;
        unsigned short* tmp = p0; p0 = p1; p1 = p2; p2 = tmp;
        gk += 32;
    }
    {   // peeled NT-2
        #pragma unroll
        for (int mi = 0; mi < 4; ++mi) aF0[mi] = *(const bf16x8*)(p0 + aOff0 + mi * 1024);
        WAITVM(0);
        BAR();
        #pragma unroll
        for (int mi = 0; mi < 4; ++mi) aF1[mi] = *(const bf16x8*)(p0 + aOff1 + mi * 1024);
        bf16x8 n00 = *(const bf16x8*)(dP0 + 32);
        bf16x8 n01 = *(const bf16x8*)(dP0 + 48);
        bf16x8 n10 = *(const bf16x8*)(dP1 + 32);
        bf16x8 n11 = *(const bf16x8*)(dP1 + 48);
        #pragma unroll
        for (int mi = 0; mi < 4; ++mi) {
            acc[mi][0] = __builtin_amdgcn_mfma_f32_32x32x16_bf16(aF0[mi], b00, acc[mi][0], 0, 0, 0);
            acc[mi][1] = __builtin_amdgcn_mfma_f32_32x32x16_bf16(aF0[mi], b10, acc[mi][1], 0, 0, 0);
            acc[mi][0] = __builtin_amdgcn_mfma_f32_32x32x16_bf16(aF1[mi], b01, acc[mi][0], 0, 0, 0);
            acc[mi][1] = __builtin_amdgcn_mfma_f32_32x32x16_bf16(aF1[mi], b11, acc[mi][1], 0, 0, 0);
        }
        BAR();
        b00 = n00; b01 = n01; b10 = n10; b11 = n11;
    }
    {   // peeled NT-1
        #pragma unroll
        for (int mi = 0; mi < 4; ++mi) aF0[mi] = *(const bf16x8*)(p1 + aOff0 + mi * 1024);
        #pragma unroll
        for (int mi = 0; mi < 4; ++mi) aF1[mi] = *(const bf16x8*)(p1 + aOff1 + mi * 1024);
        #pragma unroll
        for (int mi = 0; mi < 4; ++mi) {
            acc[mi][0] = __builtin_amdgcn_mfma_f32_32x32x16_bf16(aF0[mi], b00, acc[mi][0], 0, 0, 0);
            acc[mi][1] = __builtin_amdgcn_mfma_f32_32x32x16_bf16(aF0[mi], b10, acc[mi][1], 0, 0, 0);
            acc[mi][0] = __builtin_amdgcn_mfma_f32_32x32x16_bf16(aF1[mi], b01, acc[mi][0], 0, 0, 0);
            acc[mi][1] = __builtin_amdgcn_mfma_f32_32x32x16_bf16(aF1[mi], b11, acc[mi][1], 0, 0, 0);
        }
    }

    // epilogue: two bounce rounds; round R covers cols wn*64 + R*32 + [0,32)
    unsigned short* bounce = smemU;
    unsigned short* Op = pout + ((size_t)e * CAP + m0) * HID + n0;
    int rr = tid >> 3, colp = (tid & 7) * 8;
    int colc = wn * 32 + r;
    #pragma unroll
    for (int R = 0; R < 2; ++R) {
        __syncthreads();
        #pragma unroll
        for (int mi = 0; mi < 4; ++mi) {
            f32x16 a16 = acc[mi][R];
            #pragma unroll
            for (int rg = 0; rg < 16; ++rg) {
                int row = wm * 128 + mi * 32 + (rg & 3) + 8 * (rg >> 2) + 4 * hi2;
                bounce[row * 72 + colc] = f2bf(a16[rg]);
            }
        }
        __syncthreads();
        int gcol = (colp >> 5) * 64 + R * 32 + (colp & 31);
        #pragma unroll
        for (int j = 0; j < 8; ++j) {
            int row = rr + 32 * j;
            bf16x8 v = *(const bf16x8*)&bounce[row * 72 + colp];
            *(bf16x8*)(Op + (size_t)row * HID + gcol) = v;
        }
    }
}

// --------------------------------------------------------------- combine ----
__global__ __launch_bounds__(256) void combine_kernel(const float* __restrict__ aff,
                                                      const int* __restrict__ eidx,
                                                      const int* __restrict__ perm,
                                                      const unsigned short* __restrict__ pout,
                                                      float* __restrict__ out) {
    int t = blockIdx.x;
    int e0 = eidx[t * 2], e1 = eidx[t * 2 + 1];
    int p0 = perm[t * 2], p1 = perm[t * 2 + 1];
    bool k0 = p0 > 0, k1 = p1 > 0;
    float a0 = aff[t * NE + e0], a1 = aff[t * NE + e1];
    float denom = (k0 ? fabsf(a0) : 0.f) + ((e1 != e0 && k1) ? fabsf(a1) : 0.f);
    denom = fmaxf(denom, 1e-12f);
    float w0 = k0 ? a0 / denom : 0.f;
    float w1 = k1 ? a1 / denom : 0.f;
    int s0 = k0 ? p0 - 1 : 0;
    int s1 = k1 ? p1 - 1 : 0;
    int h = threadIdx.x * 4;
    ushort4 v0 = *(const ushort4*)(pout + (size_t)s0 * HID + h);
    ushort4 v1 = *(const ushort4*)(pout + (size_t)s1 * HID + h);
    float4 o;
    o.x = w0 * bf2f(v0.x) + w1 * bf2f(v1.x);
    o.y = w0 * bf2f(v0.y) + w1 * bf2f(v1.y);
    o.z = w0 * bf2f(v0.z) + w1 * bf2f(v1.z);
    o.w = w0 * bf2f(v0.w) + w1 * bf2f(v1.w);
    *(float4*)(out + (size_t)t * HID + h) = o;
}

// ----------------------------------------------------------------- launch ---
extern "C" void kernel_launch(void* const* d_in, const int* in_sizes, int n_in,
                              void* d_out, int out_size, void* d_ws, size_t ws_size,
                              hipStream_t stream) {
    (void)in_sizes; (void)n_in; (void)out_size; (void)ws_size;
    const float* hs   = (const float*)d_in[0];   // (T, HID)
    const float* aff  = (const float*)d_in[1];   // (T, NE)
    const float* gw   = (const float*)d_in[2];   // (NE, HID, INTER)
    const float* uw   = (const float*)d_in[3];   // (NE, HID, INTER)
    const float* dw   = (const float*)d_in[4];   // (NE, INTER, HID)
    const int*   eidx = (const int*)d_in[5];     // (T, TOPK)
    float* out = (float*)d_out;

    char* ws = (char*)d_ws;
    unsigned short* WgT    = (unsigned short*)(ws);
    unsigned short* WuT    = (unsigned short*)(ws + ((size_t)64  << 20));
    unsigned short* WdT    = (unsigned short*)(ws + ((size_t)128 << 20));
    unsigned short* Xe     = (unsigned short*)(ws + ((size_t)192 << 20));
    unsigned short* interB = (unsigned short*)(ws + ((size_t)224 << 20));
    unsigned short* pout   = (unsigned short*)(ws + ((size_t)352 << 20));
    int*            perm   = (int*)           (ws + ((size_t)416 << 20));
    int*            assign = perm + (T_TOK * TOPK);

    static int attr_set = 0;
    if (!attr_set) {
        (void)hipFuncSetAttribute((const void*)gateup_gemm,
                                  hipFuncAttributeMaxDynamicSharedMemorySize, 49152);
        (void)hipFuncSetAttribute((const void*)down_gemm,
                                  hipFuncAttributeMaxDynamicSharedMemorySize, 49152);
        attr_set = 1;
    }

    route_kernel<<<1, 512, 0, stream>>>(eidx, perm, assign);
    transpose_cvt2<<<dim3(INTER / 64, HID / 64, 16), 256, 0, stream>>>(uw, WuT, gw, WgT);
    transpose_cvt<<<dim3(HID / 64, INTER / 64, NE), 256, 0, stream>>>(dw, WdT, INTER, HID);
    gather_cvt<<<EC, 256, 0, stream>>>(hs, assign, Xe);
    gateup_gemm<<<dim3(8, 8, 64), 256, 49152, stream>>>(Xe, WgT, WuT, interB);
    down_gemm<<<dim3(8, 8, 8), 256, 49152, stream>>>(interB, WdT, pout);
    combine_kernel<<<T_TOK, 256, 0, stream>>>(aff, eidx, perm, pout, out);
}

// Round 6
// 911.473 us; speedup vs baseline: 1.2543x; 1.2543x over previous
//
#include <hip/hip_runtime.h>
#include <stdint.h>

// Problem constants (match reference)
#define T_TOK 8192
#define HID   1024
#define INTER 4096
#define NE    8
#define TOPK  2
#define CAP   2048            // min(ceil(T*K*CF/E), T) = 2048
#define EC    (NE * CAP)      // 16384 slots

// Workspace layout (bytes).
//  [0,   64MB)  WgT  bf16 (E, INTER, HID)   gate_w transposed
//  [64,  128MB) WuT  bf16 (E, INTER, HID)
//  [128, 192MB) WdT  bf16 (E, HID, INTER)   down_w transposed
//  [192, 224MB) Xe   bf16 (EC, HID)         gathered tokens
//  [224, 352MB) interB bf16 (EC, INTER)     silu(g)*u
//  [352, 384MB) pout bf16 (EC, HID)         permuted expert output
//  [416MB .. )  perm int (T,2), assign int (EC)

typedef __attribute__((ext_vector_type(8))) short bf16x8;
typedef __attribute__((ext_vector_type(4))) float f32x4;

static __device__ __forceinline__ unsigned short f2bf(float f) {
    union { float f; unsigned u; } a; a.f = f;
    unsigned r = a.u + 0x7FFFu + ((a.u >> 16) & 1u);   // round-nearest-even
    return (unsigned short)(r >> 16);
}
static __device__ __forceinline__ float bf2f(unsigned short b) {
    union { unsigned u; float f; } a; a.u = ((unsigned)b) << 16;
    return a.f;
}

static __device__ __forceinline__ void gload(const unsigned short* g, unsigned short* l) {
    // async global->LDS, 16B/lane; LDS dest = wave-uniform base + lane*16
    __builtin_amdgcn_global_load_lds((__attribute__((address_space(1))) void*)(uintptr_t)g,
                                     (__attribute__((address_space(3))) void*)l, 16, 0, 0);
}

#define BAR() do { asm volatile("" ::: "memory"); __builtin_amdgcn_s_barrier(); asm volatile("" ::: "memory"); } while (0)
#define WAITVM(N) asm volatile("s_waitcnt vmcnt(" #N ")" ::: "memory")

// ---------------------------------------------------------------- routing ---
__global__ __launch_bounds__(512) void route_kernel(const int* __restrict__ eidx,
                                                    int* __restrict__ perm,
                                                    int* __restrict__ assign) {
    int tid = threadIdx.x;
    for (int i = tid; i < EC; i += 512) assign[i] = 0;   // empty slot -> token 0
    __syncthreads();
    int e = tid >> 6;          // wave index == expert
    int lane = tid & 63;
    const int TPL = T_TOK / 64;                          // 128 tokens per lane
    int t0 = lane * TPL;
    int cnt = 0;
    for (int t = t0; t < t0 + TPL; ++t) {
        int e0 = eidx[t * 2], e1 = eidx[t * 2 + 1];
        cnt += (e0 == e) + (e1 == e);
    }
    int incl = cnt;
    #pragma unroll
    for (int off = 1; off < 64; off <<= 1) {
        int n = __shfl_up(incl, off, 64);
        if (lane >= off) incl += n;
    }
    int run = incl - cnt;
    for (int t = t0; t < t0 + TPL; ++t) {
        int e0 = eidx[t * 2], e1 = eidx[t * 2 + 1];
        int c = (e0 == e) + (e1 == e);
        if (c) {
            run += c;
            int pos = run;                       // inclusive (1-based)
            bool keep = (pos <= CAP);
            int pi = keep ? (pos + e * CAP) : 0;
            if (e0 == e) perm[t * 2]     = pi;
            if (e1 == e) perm[t * 2 + 1] = pi;
            if (keep) assign[pi - 1] = t;
        }
    }
}

// --------------------------------------------------- transpose + fp32->bf16 --
// merged gw+uw transpose: z<8 -> (in0,out0), else (in1,out1). R=HID, C=INTER.
__global__ __launch_bounds__(256) void transpose_cvt2(const float* __restrict__ in0,
                                                      unsigned short* __restrict__ out0,
                                                      const float* __restrict__ in1,
                                                      unsigned short* __restrict__ out1) {
    __shared__ unsigned short tile[64][68];
    int z = blockIdx.z;
    const float* in = (z < 8) ? in0 : in1;
    unsigned short* out = (z < 8) ? out0 : out1;
    int e = z & 7;
    const int R = HID, Cc = INTER;
    const float* inp = in + (size_t)e * R * Cc;
    unsigned short* outp = out + (size_t)e * R * Cc;
    int c0 = blockIdx.x * 64, r0 = blockIdx.y * 64;
    int t = threadIdx.x;
    int x = t & 15;
    int ry = t >> 4;
    #pragma unroll
    for (int j = 0; j < 4; ++j) {
        int row = ry + 16 * j;
        float4 v = *(const float4*)(inp + (size_t)(r0 + row) * Cc + c0 + 4 * x);
        ushort4 o;
        o.x = f2bf(v.x); o.y = f2bf(v.y); o.z = f2bf(v.z); o.w = f2bf(v.w);
        *(ushort4*)&tile[row][4 * x] = o;
    }
    __syncthreads();
    #pragma unroll
    for (int j = 0; j < 4; ++j) {
        int oc = ry + 16 * j;
        ushort4 o;
        o.x = tile[4 * x + 0][oc];
        o.y = tile[4 * x + 1][oc];
        o.z = tile[4 * x + 2][oc];
        o.w = tile[4 * x + 3][oc];
        *(ushort4*)(outp + (size_t)(c0 + oc) * R + r0 + 4 * x) = o;
    }
}

__global__ __launch_bounds__(256) void transpose_cvt(const float* __restrict__ in,
                                                     unsigned short* __restrict__ out,
                                                     int R, int Cc) {
    __shared__ unsigned short tile[64][68];
    int e = blockIdx.z;
    const float* inp = in + (size_t)e * R * Cc;
    unsigned short* outp = out + (size_t)e * R * Cc;
    int c0 = blockIdx.x * 64, r0 = blockIdx.y * 64;
    int t = threadIdx.x;
    int x = t & 15;
    int ry = t >> 4;
    #pragma unroll
    for (int j = 0; j < 4; ++j) {
        int row = ry + 16 * j;
        float4 v = *(const float4*)(inp + (size_t)(r0 + row) * Cc + c0 + 4 * x);
        ushort4 o;
        o.x = f2bf(v.x); o.y = f2bf(v.y); o.z = f2bf(v.z); o.w = f2bf(v.w);
        *(ushort4*)&tile[row][4 * x] = o;
    }
    __syncthreads();
    #pragma unroll
    for (int j = 0; j < 4; ++j) {
        int oc = ry + 16 * j;
        ushort4 o;
        o.x = tile[4 * x + 0][oc];
        o.y = tile[4 * x + 1][oc];
        o.z = tile[4 * x + 2][oc];
        o.w = tile[4 * x + 3][oc];
        *(ushort4*)(outp + (size_t)(c0 + oc) * R + r0 + 4 * x) = o;
    }
}

// ------------------------------------------------------- gather + cvt tokens -
__global__ __launch_bounds__(256) void gather_cvt(const float* __restrict__ hs,
                                                  const int* __restrict__ assign,
                                                  unsigned short* __restrict__ xe) {
    int s = blockIdx.x;
    int tok = assign[s];
    const float* src = hs + (size_t)tok * HID;
    unsigned short* dst = xe + (size_t)s * HID;
    int h = threadIdx.x * 4;
    float4 v = *(const float4*)(src + h);
    ushort4 o;
    o.x = f2bf(v.x); o.y = f2bf(v.y); o.z = f2bf(v.z); o.w = f2bf(v.w);
    *(ushort4*)(dst + h) = o;
}

// =============================================================================
// R5 = R2 structure with MERGED single-phase K-tile (barriers per tile 4 -> 2).
// 2-block/CU GEMMs. 256 threads = 4 waves (2M x 2N); BM=256, BK=32.
// Triple-buffered LDS, 72 KiB/block -> 2 blocks/CU; two independent barrier
// groups overlap MFMA vs LDS/VMEM phases (m114).
// Per buffer (12288 elems = 24 KiB): A [0,8192) = 256r x 32k;
//   R1 [8192,10240) = 64r x 32k; R2 [10240,12288) = 64r x 32k.
// Swizzle (64B rows, 4 chunks of 16B): chunk ^= (row>>1)&3. Writer
// pre-swizzles the GLOBAL column (rule #21); LDS dest stays linear.
// Per K-tile t (merged): {12 ds_reads (aF x8 + B x4) | 6 stage gloads (t+2) |
//   WAITVM(6) | BAR | 32 MFMA (setprio) | BAR}.
// Invariant: at iter t's WAITVM(6), outstanding = [t+1: 6][t+2: 6]; wait
// retires exactly t+1's. Prologue: stage t0+t1, WAITVM(6)+BAR retires t0.
// =============================================================================

#define BUFE 12288

#define MFMA16(ACC, O, B0, B1) \
    _Pragma("unroll") \
    for (int mi = 0; mi < 8; ++mi) { \
        ACC[mi][O]     = __builtin_amdgcn_mfma_f32_16x16x32_bf16(aF[mi], B0, ACC[mi][O], 0, 0, 0); \
        ACC[mi][O + 1] = __builtin_amdgcn_mfma_f32_16x16x32_bf16(aF[mi], B1, ACC[mi][O + 1], 0, 0, 0); \
    }

#define LOAD_AF(rd) \
    _Pragma("unroll") \
    for (int mi = 0; mi < 8; ++mi) aF[mi] = *(const bf16x8*)((rd) + aRd + mi * 512);

// ------------------------------- fused gate+up GEMM + SiLU*mul (dual acc) ----
__global__ __launch_bounds__(256, 2) void gateup_gemm(const unsigned short* __restrict__ Xe,
                                                      const unsigned short* __restrict__ WgT,
                                                      const unsigned short* __restrict__ WuT,
                                                      unsigned short* __restrict__ interB) {
    extern __shared__ __align__(16) unsigned short smemU[];
    const int K = HID;          // 1024
    const int NT = K / 32;      // 32 K-tiles

    int e  = blockIdx.x;                 // x fastest -> XCD-pinned per expert
    int m0 = blockIdx.y * 256;
    int n0 = blockIdx.z * 64;

    int tid = threadIdx.x;
    int lane = tid & 63, w = tid >> 6;
    int lm = lane & 15, hi = lane >> 4;
    int wm = w >> 1, wn = w & 1;

    const int swz  = (hi ^ ((lm >> 1) & 3)) << 3;
    const int aRd  = (wm * 128 + lm) * 32 + swz;
    const int r1Rd = 8192  + (wn * 32 + lm) * 32 + swz;
    const int r2Rd = 10240 + (wn * 32 + lm) * 32 + swz;

    int sr = lane >> 2;
    int sc = ((lane & 3) ^ ((lane >> 3) & 3)) << 3;   // pre-swizzled global col
    const unsigned short* aS = Xe  + ((size_t)e * CAP   + m0 + w * 64 + sr) * K + sc;
    const unsigned short* gS = WgT + ((size_t)e * INTER + n0 + w * 16 + sr) * K + sc;
    const unsigned short* uS = WuT + ((size_t)e * INTER + n0 + w * 16 + sr) * K + sc;
    const int dA = w * 2048;           // + j*512
    const int dG = 8192  + w * 512;
    const int dU = 10240 + w * 512;

    f32x4 zero = {0.f, 0.f, 0.f, 0.f};
    f32x4 accG[8][2], accU[8][2];
    #pragma unroll
    for (int i = 0; i < 8; ++i) {
        accG[i][0] = zero; accG[i][1] = zero;
        accU[i][0] = zero; accU[i][1] = zero;
    }

    unsigned short* p0 = smemU;
    unsigned short* p1 = smemU + BUFE;
    unsigned short* p2 = smemU + 2 * BUFE;

    // prologue: stage tiles 0 (buf0) and 1 (buf1); FIFO [A*4,G,U] x2
    {
        #pragma unroll
        for (int j = 0; j < 4; ++j) gload(aS + (size_t)j * 16 * K, p0 + dA + j * 512);
        gload(gS, p0 + dG); gload(uS, p0 + dU);
        #pragma unroll
        for (int j = 0; j < 4; ++j) gload(aS + (size_t)j * 16 * K + 32, p1 + dA + j * 512);
        gload(gS + 32, p1 + dG); gload(uS + 32, p1 + dU);
        WAITVM(6);             // retire tile-0's 6; tile-1's 6 in flight
        BAR();
    }

    bf16x8 aF[8];
    int gk = 64;
    for (int t = 0; t < NT - 2; ++t) {
        const unsigned short* rd = p0;
        unsigned short* wr = p2;
        // merged phase: all reads, all stages, one wait, one barrier, 32 MFMA
        LOAD_AF(rd);
        bf16x8 g0 = *(const bf16x8*)(rd + r1Rd);
        bf16x8 g1 = *(const bf16x8*)(rd + r1Rd + 512);
        bf16x8 u0 = *(const bf16x8*)(rd + r2Rd);
        bf16x8 u1 = *(const bf16x8*)(rd + r2Rd + 512);
        #pragma unroll
        for (int j = 0; j < 4; ++j) gload(aS + (size_t)j * 16 * K + gk, wr + dA + j * 512);
        gload(gS + gk, wr + dG);
        gload(uS + gk, wr + dU);
        WAITVM(6);
        BAR();
        __builtin_amdgcn_s_setprio(1);
        MFMA16(accG, 0, g0, g1);
        MFMA16(accU, 0, u0, u1);
        __builtin_amdgcn_s_setprio(0);
        BAR();
        // rotate buffers
        unsigned short* tmp = p0; p0 = p1; p1 = p2; p2 = tmp;
        gk += 32;
    }
    // ---- peeled tile NT-2 (no stages; retire tile NT-1)
    {
        const unsigned short* rd = p0;
        LOAD_AF(rd);
        bf16x8 g0 = *(const bf16x8*)(rd + r1Rd);
        bf16x8 g1 = *(const bf16x8*)(rd + r1Rd + 512);
        bf16x8 u0 = *(const bf16x8*)(rd + r2Rd);
        bf16x8 u1 = *(const bf16x8*)(rd + r2Rd + 512);
        WAITVM(0);
        BAR();
        MFMA16(accG, 0, g0, g1);
        MFMA16(accU, 0, u0, u1);
        BAR();
    }
    // ---- peeled tile NT-1
    {
        const unsigned short* rd = p1;
        LOAD_AF(rd);
        bf16x8 g0 = *(const bf16x8*)(rd + r1Rd);
        bf16x8 g1 = *(const bf16x8*)(rd + r1Rd + 512);
        bf16x8 u0 = *(const bf16x8*)(rd + r2Rd);
        bf16x8 u1 = *(const bf16x8*)(rd + r2Rd + 512);
        MFMA16(accG, 0, g0, g1);
        MFMA16(accU, 0, u0, u1);
    }

    // epilogue: silu(G)*U -> bounce [256][72] -> vector stores
    __syncthreads();
    unsigned short* bounce = smemU;
    #pragma unroll
    for (int mi = 0; mi < 8; ++mi)
        #pragma unroll
        for (int nf = 0; nf < 2; ++nf) {
            f32x4 g4 = accG[mi][nf], u4 = accU[mi][nf];
            #pragma unroll
            for (int r = 0; r < 4; ++r) {
                int row = wm * 128 + mi * 16 + (lane >> 4) * 4 + r;
                int col = wn * 32 + nf * 16 + lm;
                float g = g4[r];
                float s = g / (1.f + __expf(-g)) * u4[r];
                bounce[row * 72 + col] = f2bf(s);
            }
        }
    __syncthreads();
    {
        unsigned short* Op = interB + ((size_t)e * CAP + m0) * INTER + n0;
        int rr = tid >> 3, cc = (tid & 7) * 8;
        #pragma unroll
        for (int j = 0; j < 8; ++j) {
            int row = rr + 32 * j;
            bf16x8 v = *(const bf16x8*)&bounce[row * 72 + cc];
            *(bf16x8*)(Op + (size_t)row * INTER + cc) = v;
        }
    }
}

// ------------------------------------------------------------- down GEMM ----
__global__ __launch_bounds__(256, 2) void down_gemm(const unsigned short* __restrict__ interB,
                                                    const unsigned short* __restrict__ WdT,
                                                    unsigned short* __restrict__ pout) {
    extern __shared__ __align__(16) unsigned short smemU[];
    const int K = INTER;        // 4096
    const int NT = K / 32;      // 128 K-tiles

    int e  = blockIdx.x;
    int m0 = blockIdx.y * 256;
    int n0 = blockIdx.z * 128;

    int tid = threadIdx.x;
    int lane = tid & 63, w = tid >> 6;
    int lm = lane & 15, hi = lane >> 4;
    int wm = w >> 1, wn = w & 1;

    const int swz  = (hi ^ ((lm >> 1) & 3)) << 3;
    const int aRd  = (wm * 128 + lm) * 32 + swz;
    const int r1Rd = 8192  + (wn * 32 + lm) * 32 + swz;
    const int r2Rd = 10240 + (wn * 32 + lm) * 32 + swz;

    int sr = lane >> 2;
    int sc = ((lane & 3) ^ ((lane >> 3) & 3)) << 3;
    const unsigned short* aS = interB + ((size_t)e * CAP + m0 + w * 64 + sr) * K + sc;
    int rb1 = (w >> 1) * 64 + (w & 1) * 16;       // R1 LDS rows w*16.. map here
    const unsigned short* b1S = WdT + ((size_t)e * HID + n0 + rb1 + sr) * K + sc;
    const unsigned short* b2S = WdT + ((size_t)e * HID + n0 + rb1 + 32 + sr) * K + sc;
    const int dA = w * 2048;
    const int d1 = 8192  + w * 512;
    const int d2 = 10240 + w * 512;

    f32x4 zero = {0.f, 0.f, 0.f, 0.f};
    f32x4 acc[8][4];
    #pragma unroll
    for (int i = 0; i < 8; ++i)
        #pragma unroll
        for (int j = 0; j < 4; ++j) acc[i][j] = zero;

    unsigned short* p0 = smemU;
    unsigned short* p1 = smemU + BUFE;
    unsigned short* p2 = smemU + 2 * BUFE;

    {
        #pragma unroll
        for (int j = 0; j < 4; ++j) gload(aS + (size_t)j * 16 * K, p0 + dA + j * 512);
        gload(b1S, p0 + d1); gload(b2S, p0 + d2);
        #pragma unroll
        for (int j = 0; j < 4; ++j) gload(aS + (size_t)j * 16 * K + 32, p1 + dA + j * 512);
        gload(b1S + 32, p1 + d1); gload(b2S + 32, p1 + d2);
        WAITVM(6);
        BAR();
    }

    bf16x8 aF[8];
    int gk = 64;
    for (int t = 0; t < NT - 2; ++t) {
        const unsigned short* rd = p0;
        unsigned short* wr = p2;
        LOAD_AF(rd);
        bf16x8 b0 = *(const bf16x8*)(rd + r1Rd);
        bf16x8 b1 = *(const bf16x8*)(rd + r1Rd + 512);
        bf16x8 b2 = *(const bf16x8*)(rd + r2Rd);
        bf16x8 b3 = *(const bf16x8*)(rd + r2Rd + 512);
        #pragma unroll
        for (int j = 0; j < 4; ++j) gload(aS + (size_t)j * 16 * K + gk, wr + dA + j * 512);
        gload(b1S + gk, wr + d1);
        gload(b2S + gk, wr + d2);
        WAITVM(6);
        BAR();
        __builtin_amdgcn_s_setprio(1);
        MFMA16(acc, 0, b0, b1);
        MFMA16(acc, 2, b2, b3);
        __builtin_amdgcn_s_setprio(0);
        BAR();
        unsigned short* tmp = p0; p0 = p1; p1 = p2; p2 = tmp;
        gk += 32;
    }
    {   // peeled NT-2
        const unsigned short* rd = p0;
        LOAD_AF(rd);
        bf16x8 b0 = *(const bf16x8*)(rd + r1Rd);
        bf16x8 b1 = *(const bf16x8*)(rd + r1Rd + 512);
        bf16x8 b2 = *(const bf16x8*)(rd + r2Rd);
        bf16x8 b3 = *(const bf16x8*)(rd + r2Rd + 512);
        WAITVM(0);
        BAR();
        MFMA16(acc, 0, b0, b1);
        MFMA16(acc, 2, b2, b3);
        BAR();
    }
    {   // peeled NT-1
        const unsigned short* rd = p1;
        LOAD_AF(rd);
        bf16x8 b0 = *(const bf16x8*)(rd + r1Rd);
        bf16x8 b1 = *(const bf16x8*)(rd + r1Rd + 512);
        bf16x8 b2 = *(const bf16x8*)(rd + r2Rd);
        bf16x8 b3 = *(const bf16x8*)(rd + r2Rd + 512);
        MFMA16(acc, 0, b0, b1);
        MFMA16(acc, 2, b2, b3);
    }

    // epilogue: two bounce rounds; round R covers cols wn*64 + R*32 + [0,32)
    unsigned short* bounce = smemU;
    unsigned short* Op = pout + ((size_t)e * CAP + m0) * HID + n0;
    int rr = tid >> 3, c8 = tid & 7;
    int colp = c8 * 8;
    #pragma unroll
    for (int R = 0; R < 2; ++R) {
        __syncthreads();
        #pragma unroll
        for (int mi = 0; mi < 8; ++mi)
            #pragma unroll
            for (int nf = 0; nf < 2; ++nf) {
                f32x4 a4 = acc[mi][2 * R + nf];
                #pragma unroll
                for (int r = 0; r < 4; ++r) {
                    int row = wm * 128 + mi * 16 + hi * 4 + r;
                    int col = wn * 32 + nf * 16 + lm;   // compacted col'
                    bounce[row * 72 + col] = f2bf(a4[r]);
                }
            }
        __syncthreads();
        int gcol = (colp >> 5) * 64 + R * 32 + (colp & 31);
        #pragma unroll
        for (int j = 0; j < 8; ++j) {
            int row = rr + 32 * j;
            bf16x8 v = *(const bf16x8*)&bounce[row * 72 + colp];
            *(bf16x8*)(Op + (size_t)row * HID + gcol) = v;
        }
    }
}

// --------------------------------------------------------------- combine ----
__global__ __launch_bounds__(256) void combine_kernel(const float* __restrict__ aff,
                                                      const int* __restrict__ eidx,
                                                      const int* __restrict__ perm,
                                                      const unsigned short* __restrict__ pout,
                                                      float* __restrict__ out) {
    int t = blockIdx.x;
    int e0 = eidx[t * 2], e1 = eidx[t * 2 + 1];
    int p0 = perm[t * 2], p1 = perm[t * 2 + 1];
    bool k0 = p0 > 0, k1 = p1 > 0;
    float a0 = aff[t * NE + e0], a1 = aff[t * NE + e1];
    float denom = (k0 ? fabsf(a0) : 0.f) + ((e1 != e0 && k1) ? fabsf(a1) : 0.f);
    denom = fmaxf(denom, 1e-12f);
    float w0 = k0 ? a0 / denom : 0.f;
    float w1 = k1 ? a1 / denom : 0.f;
    int s0 = k0 ? p0 - 1 : 0;
    int s1 = k1 ? p1 - 1 : 0;
    int h = threadIdx.x * 4;
    ushort4 v0 = *(const ushort4*)(pout + (size_t)s0 * HID + h);
    ushort4 v1 = *(const ushort4*)(pout + (size_t)s1 * HID + h);
    float4 o;
    o.x = w0 * bf2f(v0.x) + w1 * bf2f(v1.x);
    o.y = w0 * bf2f(v0.y) + w1 * bf2f(v1.y);
    o.z = w0 * bf2f(v0.z) + w1 * bf2f(v1.z);
    o.w = w0 * bf2f(v0.w) + w1 * bf2f(v1.w);
    *(float4*)(out + (size_t)t * HID + h) = o;
}

// ----------------------------------------------------------------- launch ---
extern "C" void kernel_launch(void* const* d_in, const int* in_sizes, int n_in,
                              void* d_out, int out_size, void* d_ws, size_t ws_size,
                              hipStream_t stream) {
    (void)in_sizes; (void)n_in; (void)out_size; (void)ws_size;
    const float* hs   = (const float*)d_in[0];   // (T, HID)
    const float* aff  = (const float*)d_in[1];   // (T, NE)
    const float* gw   = (const float*)d_in[2];   // (NE, HID, INTER)
    const float* uw   = (const float*)d_in[3];   // (NE, HID, INTER)
    const float* dw   = (const float*)d_in[4];   // (NE, INTER, HID)
    const int*   eidx = (const int*)d_in[5];     // (T, TOPK)
    float* out = (float*)d_out;

    char* ws = (char*)d_ws;
    unsigned short* WgT    = (unsigned short*)(ws);
    unsigned short* WuT    = (unsigned short*)(ws + ((size_t)64  << 20));
    unsigned short* WdT    = (unsigned short*)(ws + ((size_t)128 << 20));
    unsigned short* Xe     = (unsigned short*)(ws + ((size_t)192 << 20));
    unsigned short* interB = (unsigned short*)(ws + ((size_t)224 << 20));
    unsigned short* pout   = (unsigned short*)(ws + ((size_t)352 << 20));
    int*            perm   = (int*)           (ws + ((size_t)416 << 20));
    int*            assign = perm + (T_TOK * TOPK);

    static int attr_set = 0;
    if (!attr_set) {
        (void)hipFuncSetAttribute((const void*)gateup_gemm,
                                  hipFuncAttributeMaxDynamicSharedMemorySize, 73728);
        (void)hipFuncSetAttribute((const void*)down_gemm,
                                  hipFuncAttributeMaxDynamicSharedMemorySize, 73728);
        attr_set = 1;
    }

    route_kernel<<<1, 512, 0, stream>>>(eidx, perm, assign);
    transpose_cvt2<<<dim3(INTER / 64, HID / 64, 16), 256, 0, stream>>>(uw, WuT, gw, WgT);
    transpose_cvt<<<dim3(HID / 64, INTER / 64, NE), 256, 0, stream>>>(dw, WdT, INTER, HID);
    gather_cvt<<<EC, 256, 0, stream>>>(hs, assign, Xe);
    gateup_gemm<<<dim3(8, 8, 64), 256, 73728, stream>>>(Xe, WgT, WuT, interB);
    down_gemm<<<dim3(8, 8, 8), 256, 73728, stream>>>(interB, WdT, pout);
    combine_kernel<<<T_TOK, 256, 0, stream>>>(aff, eidx, perm, pout, out);
}